// Round 1
// baseline (281.989 us; speedup 1.0000x reference)
//
#include <hip/hip_runtime.h>
#include <hip/hip_bf16.h>
#include <cstdint>

typedef __attribute__((ext_vector_type(8))) short s16x8;
typedef __attribute__((ext_vector_type(4))) short s16x4;
typedef __attribute__((ext_vector_type(4))) float f32x4;

__device__ __forceinline__ ushort f2bf(float f){
  uint32_t u = __float_as_uint(f);
  return (ushort)((u + 0x7FFFu + ((u >> 16) & 1u)) >> 16);
}
__device__ __forceinline__ float bf2f(ushort h){
  return __uint_as_float(((uint32_t)h) << 16);
}
__device__ __forceinline__ void gload16(const void* g, void* l){
  __builtin_amdgcn_global_load_lds((const __attribute__((address_space(1))) void*)g,
                                   (__attribute__((address_space(3))) void*)l, 16, 0, 0);
}

// ---------------- pre-pass: split fp32 -> bf16 hi/lo ----------------
__global__ void split_f32(const float* __restrict__ in, ushort* __restrict__ hi,
                          ushort* __restrict__ lo, int n4){
  int i = blockIdx.x * blockDim.x + threadIdx.x;
  if (i >= n4) return;
  const f32x4 v = ((const f32x4*)in)[i];
  s16x4 h, l;
#pragma unroll
  for (int j = 0; j < 4; ++j){
    ushort hb = f2bf(v[j]);
    h[j] = (short)hb;
    l[j] = (short)f2bf(v[j] - bf2f(hb));
  }
  ((s16x4*)hi)[i] = h;
  ((s16x4*)lo)[i] = l;
}

// split + transpose: in[K][N] -> outT[N][K] (bf16 hi/lo)
__global__ void transpose_split(const float* __restrict__ in, ushort* __restrict__ hiT,
                                ushort* __restrict__ loT, int K, int N){
  __shared__ float tile[32][33];
  const int kb = blockIdx.y * 32, nb = blockIdx.x * 32;
  const int tx = threadIdx.x & 31, ty = threadIdx.x >> 5;  // ty: 0..7
#pragma unroll
  for (int r = 0; r < 32; r += 8)
    tile[ty + r][tx] = in[(size_t)(kb + ty + r) * N + nb + tx];
  __syncthreads();
#pragma unroll
  for (int r = 0; r < 32; r += 8){
    float v = tile[tx][ty + r];
    ushort hb = f2bf(v);
    size_t o = (size_t)(nb + ty + r) * K + kb + tx;
    hiT[o] = hb;
    loT[o] = f2bf(v - bf2f(hb));
  }
}

// W3 (512x10 f32) -> W3T (10x512 f32)
__global__ void transpose_w3(const float* __restrict__ W3, float* __restrict__ W3T){
  const int k = threadIdx.x;  // 512 threads
#pragma unroll
  for (int c = 0; c < 10; ++c) W3T[c * 512 + k] = W3[k * 10 + c];
}

// ---------------- split-bf16 GEMM (3-term bf16x3), fused bias+act ----------------
// A: M x K row-major as hi/lo bf16.  B: N x K row-major (pre-transposed weights) hi/lo.
// MODE 0: blend_act, write outHi/outLo bf16 pair.  MODE 1: relu, write outHi bf16.
template<int MODE>
__global__ __launch_bounds__(256, 2)
void gemm_split(const ushort* __restrict__ Ahi, const ushort* __restrict__ Alo,
                const ushort* __restrict__ Bhi, const ushort* __restrict__ Blo,
                const float* __restrict__ bias,
                ushort* __restrict__ outHi, ushort* __restrict__ outLo,
                int N, int K)
{
  __shared__ ushort lds[4 * 8192];  // planes: Ahi, Alo, Bhi, Blo; each [128][64], 128B rows
  const int t = threadIdx.x;
  const int lane = t & 63;
  const int wr = (t >> 7) & 1;   // wave row (wid>>1)
  const int wc = (t >> 6) & 1;   // wave col (wid&1)

  // XCD-aware bijective swizzle (grid count divisible by 8)
  const int gx = gridDim.x;
  const int nwg = gx * gridDim.y;
  const int bid = blockIdx.y * gx + blockIdx.x;
  const int swz = (bid & 7) * (nwg >> 3) + (bid >> 3);
  const int m0 = (swz / gx) * 128;
  const int n0 = (swz % gx) * 128;

  const int srow = t >> 3;               // staging row within 32-row chunk
  const int kb_sw = (t & 7) << 4;        // swizzled kbyte slot

  const ushort* gb0 = Ahi + (size_t)m0 * K;
  const ushort* gb1 = Alo + (size_t)m0 * K;
  const ushort* gb2 = Bhi + (size_t)n0 * K;
  const ushort* gb3 = Blo + (size_t)n0 * K;

  f32x4 acc[4][4] = {};

  for (int kt = 0; kt < K; kt += 64){
    __syncthreads();
    const ushort* gp[4] = {gb0, gb1, gb2, gb3};
#pragma unroll
    for (int p = 0; p < 4; ++p){
#pragma unroll
      for (int j = 0; j < 4; ++j){
        const int row = j * 32 + srow;
        const int kbyte = kb_sw ^ ((row & 7) << 4);  // inverse-swizzled global source
        gload16(gp[p] + (size_t)row * K + kt + (kbyte >> 1),
                &lds[p * 8192 + row * 64 + ((t & 7) << 3)]);  // linear LDS dest
      }
    }
    __syncthreads();  // drains vmcnt(0): staged data visible
#pragma unroll
    for (int s = 0; s < 2; ++s){
      s16x8 af[2][4], bfv[2][4];
      const int kb = (s << 6) + ((lane >> 4) << 4);
#pragma unroll
      for (int h = 0; h < 2; ++h){
#pragma unroll
        for (int i = 0; i < 4; ++i){
          const int ar = wr * 64 + i * 16 + (lane & 15);
          af[h][i] = *(const s16x8*)&lds[h * 8192 + ar * 64 + ((kb ^ ((ar & 7) << 4)) >> 1)];
          const int br = wc * 64 + i * 16 + (lane & 15);
          bfv[h][i] = *(const s16x8*)&lds[(2 + h) * 8192 + br * 64 + ((kb ^ ((br & 7) << 4)) >> 1)];
        }
      }
#pragma unroll
      for (int i = 0; i < 4; ++i)
#pragma unroll
        for (int j = 0; j < 4; ++j){
          acc[i][j] = __builtin_amdgcn_mfma_f32_16x16x32_bf16(af[0][i], bfv[0][j], acc[i][j], 0, 0, 0);
          acc[i][j] = __builtin_amdgcn_mfma_f32_16x16x32_bf16(af[0][i], bfv[1][j], acc[i][j], 0, 0, 0);
          acc[i][j] = __builtin_amdgcn_mfma_f32_16x16x32_bf16(af[1][i], bfv[0][j], acc[i][j], 0, 0, 0);
        }
    }
  }

  // epilogue: C frag layout col = lane&15, row = (lane>>4)*4 + r  [measured m89/m91]
  const int rb = m0 + wr * 64 + ((lane >> 4) << 2);
  const int cb = n0 + wc * 64 + (lane & 15);
#pragma unroll
  for (int j = 0; j < 4; ++j){
    const int col = cb + j * 16;
    const float bv = bias[col];
#pragma unroll
    for (int i = 0; i < 4; ++i){
#pragma unroll
      for (int r = 0; r < 4; ++r){
        const int row = rb + i * 16 + r;
        const float v = acc[i][j][r] + bv;
        const size_t o = (size_t)row * N + col;
        if (MODE == 0){
          const float th = tanhf(v);
          const float a = v > 0.f ? v * 0.9f + th * 0.1f : th * 0.5f;
          const ushort hb = f2bf(a);
          outHi[o] = hb;
          outLo[o] = f2bf(a - bf2f(hb));
        } else {
          const float a = v > 0.f ? v : 0.f;
          outHi[o] = f2bf(a);
        }
      }
    }
  }
}

// ---------------- tiny GEMM3: out[32768][10] = h2 @ W3 + b3 ----------------
__global__ void gemm3(const ushort* __restrict__ h2, const float* __restrict__ W3T,
                      const float* __restrict__ b3, float* __restrict__ out){
  const int lane = threadIdx.x & 63;
  const int row = blockIdx.x * 4 + (threadIdx.x >> 6);  // one wave per row
  const s16x8 hv = *(const s16x8*)(h2 + (size_t)row * 512 + lane * 8);
  float hf[8];
#pragma unroll
  for (int j = 0; j < 8; ++j) hf[j] = bf2f((ushort)hv[j]);
  float acc[10];
#pragma unroll
  for (int c = 0; c < 10; ++c){
    const f32x4 w0 = *(const f32x4*)(W3T + c * 512 + lane * 8);
    const f32x4 w1 = *(const f32x4*)(W3T + c * 512 + lane * 8 + 4);
    float a = 0.f;
#pragma unroll
    for (int j = 0; j < 4; ++j) a += hf[j] * w0[j];
#pragma unroll
    for (int j = 0; j < 4; ++j) a += hf[4 + j] * w1[j];
    acc[c] = a;
  }
#pragma unroll
  for (int off = 32; off; off >>= 1)
#pragma unroll
    for (int c = 0; c < 10; ++c) acc[c] += __shfl_xor(acc[c], off);
  if (lane == 0){
#pragma unroll
    for (int c = 0; c < 10; ++c) out[(size_t)row * 10 + c] = acc[c] + b3[c];
  }
}

extern "C" void kernel_launch(void* const* d_in, const int* in_sizes, int n_in,
                              void* d_out, int out_size, void* d_ws, size_t ws_size,
                              hipStream_t stream){
  const float* x  = (const float*)d_in[0];
  const float* W1 = (const float*)d_in[1];
  const float* b1 = (const float*)d_in[2];
  const float* W2 = (const float*)d_in[3];
  const float* b2 = (const float*)d_in[4];
  const float* W3 = (const float*)d_in[5];
  const float* b3 = (const float*)d_in[6];
  float* out = (float*)d_out;

  const int B = 32768, Din = 512, H = 1024, Hh = 512;
  char* ws = (char*)d_ws;
  const size_t MB = (size_t)1 << 20;
  // ws layout (~196.5 MB):
  ushort* h1hi  = (ushort*)(ws);                 // 64 MB
  ushort* h1lo  = (ushort*)(ws + 64 * MB);       // 64 MB
  ushort* xhi   = (ushort*)(ws + 128 * MB);      // 32 MB (reused as h2 after gemm1)
  ushort* xlo   = (ushort*)(ws + 160 * MB);      // 32 MB
  ushort* h2    = xhi;
  ushort* W1hiT = (ushort*)(ws + 192 * MB);      // 1 MB each
  ushort* W1loT = W1hiT + (size_t)Din * H;
  ushort* W2hiT = W1loT + (size_t)Din * H;
  ushort* W2loT = W2hiT + (size_t)H * Hh;
  float*  W3T   = (float*)(W2loT + (size_t)H * Hh);

  split_f32<<<(B * Din / 4 + 255) / 256, 256, 0, stream>>>(x, xhi, xlo, B * Din / 4);
  transpose_split<<<dim3(H / 32, Din / 32), 256, 0, stream>>>(W1, W1hiT, W1loT, Din, H);
  transpose_split<<<dim3(Hh / 32, H / 32), 256, 0, stream>>>(W2, W2hiT, W2loT, H, Hh);
  transpose_w3<<<1, 512, 0, stream>>>(W3, W3T);

  gemm_split<0><<<dim3(H / 128, B / 128), 256, 0, stream>>>(
      xhi, xlo, W1hiT, W1loT, b1, h1hi, h1lo, H, Din);
  gemm_split<1><<<dim3(Hh / 128, B / 128), 256, 0, stream>>>(
      h1hi, h1lo, W2hiT, W2loT, b2, h2, (ushort*)nullptr, Hh, H);
  gemm3<<<B / 4, 256, 0, stream>>>(h2, W3T, b3, out);
}

// Round 5
// 153.278 us; speedup vs baseline: 1.8397x; 1.8397x over previous
//
#include <hip/hip_runtime.h>
#include <hip/hip_bf16.h>
#include <hip/hip_fp16.h>
#include <cstdint>

typedef __attribute__((ext_vector_type(8))) short s16x8;
typedef __attribute__((ext_vector_type(4))) short s16x4;
typedef __attribute__((ext_vector_type(8))) _Float16 f16x8;
typedef __attribute__((ext_vector_type(4))) _Float16 f16x4;
typedef __attribute__((ext_vector_type(4))) float f32x4;

__device__ __forceinline__ void gload16(const void* g, void* l){
  __builtin_amdgcn_global_load_lds((const __attribute__((address_space(1))) void*)g,
                                   (__attribute__((address_space(3))) void*)l, 16, 0, 0);
}

// ---------------- pre-pass: fp32 -> fp16 ----------------
__global__ void convert_f16(const float* __restrict__ in, ushort* __restrict__ out, int n4){
  int i = blockIdx.x * blockDim.x + threadIdx.x;
  if (i >= n4) return;
  const f32x4 v = ((const f32x4*)in)[i];
  f16x4 o;
#pragma unroll
  for (int j = 0; j < 4; ++j) o[j] = (_Float16)v[j];
  ((f16x4*)out)[i] = o;
}

// transpose + convert: in[K][N] f32 -> outT[N][K] fp16
__global__ void transpose_f16(const float* __restrict__ in, ushort* __restrict__ outT,
                              int K, int N){
  __shared__ float tile[32][33];
  const int kb = blockIdx.y * 32, nb = blockIdx.x * 32;
  const int tx = threadIdx.x & 31, ty = threadIdx.x >> 5;  // ty: 0..7
#pragma unroll
  for (int r = 0; r < 32; r += 8)
    tile[ty + r][tx] = in[(size_t)(kb + ty + r) * N + nb + tx];
  __syncthreads();
#pragma unroll
  for (int r = 0; r < 32; r += 8){
    const float v = tile[tx][ty + r];
    const _Float16 h = (_Float16)v;
    outT[(size_t)(nb + ty + r) * K + kb + tx] = __builtin_bit_cast(ushort, h);
  }
}

// W3 (512x10 f32) -> W3T (10x512 f32)
__global__ void transpose_w3(const float* __restrict__ W3, float* __restrict__ W3T){
  const int k = threadIdx.x;  // 512 threads
#pragma unroll
  for (int c = 0; c < 10; ++c) W3T[c * 512 + k] = W3[k * 10 + c];
}

// ---------------- 256x256-tile fp16 GEMM, 4-phase double-buffered pipeline --------
// A: M x K fp16 row-major.  B: N x K fp16 row-major (pre-transposed weights).
// 8 waves (2M x 4N), per-wave 128x64 output. LDS 128 KB:
//   A plane p at halfword p*16384 (rows 0-255 x 64 k), B plane p at 32768+p*16384.
// Iteration u reads plane (u&1), stages tile u+1 into plane (u&1)^1 at p0/p1.
// Tile boundary: s_waitcnt vmcnt(0) + s_barrier (per-wave vmcnt alone is NOT
// enough: wave X reads rows staged by wave Y -- the barrier publishes them).
// MODE 0: blend_act -> fp16 out.  MODE 1: relu -> fp16 out.
template<int MODE>
__global__ __launch_bounds__(512, 2)
void gemm_f16_256(const ushort* __restrict__ A, const ushort* __restrict__ Bw,
                  const float* __restrict__ bias, ushort* __restrict__ out,
                  int N, int K)
{
  __shared__ ushort lds[65536];
  const int t = threadIdx.x;
  const int lane = t & 63;
  const int w = t >> 6;
  const int wm = w >> 2, wn = w & 3;       // wave grid 2(M) x 4(N)
  const int ln15 = lane & 15, lnHi = lane >> 4;

  // XCD-aware bijective swizzle (nwg divisible by 8)
  const int gx = gridDim.x;
  const int nwg = gx * gridDim.y;
  const int bid = blockIdx.y * gx + blockIdx.x;
  const int swz = (bid & 7) * (nwg >> 3) + (bid >> 3);
  const int m0 = (swz / gx) * 256;
  const int n0 = (swz % gx) * 256;

  const ushort* gA = A + (size_t)m0 * K;
  const ushort* gB = Bw + (size_t)n0 * K;
  const int NT = K >> 6;

  // stage one 16KB half-tile (128 rows x 64 k). LDS dest is linear in lane
  // (wave-uniform base + lane*16B); global source carries the inverse XOR
  // swizzle so reads can use byte ^= (row&7)<<4.
  auto STAGE = [&](const ushort* gbase, ushort* lbase){
#pragma unroll
    for (int c = 0; c < 2; ++c){
      const int chunk = c * 512 + t;
      const int row = chunk >> 3, slot = chunk & 7;
      const int kb = (slot << 4) ^ ((row & 7) << 4);
      gload16(gbase + (size_t)row * K + (kb >> 1), lbase + row * 64 + slot * 8);
    }
  };
  auto readA = [&](f16x8* af, const ushort* base, int mh, int kh){
    const int kb = kh * 64 + lnHi * 16;
#pragma unroll
    for (int m = 0; m < 4; ++m){
      const int row = wm * 128 + (mh * 4 + m) * 16 + ln15;
      af[m] = *(const f16x8*)&base[row * 64 + ((kb ^ ((row & 7) << 4)) >> 1)];
    }
  };
  auto readB = [&](f16x8* bf, const ushort* base, int kh){
    const int kb = kh * 64 + lnHi * 16;
#pragma unroll
    for (int n = 0; n < 4; ++n){
      const int row = wn * 64 + n * 16 + ln15;
      bf[n] = *(const f16x8*)&base[row * 64 + ((kb ^ ((row & 7) << 4)) >> 1)];
    }
  };

  f32x4 acc[8][4] = {};

  // ---- prologue: stage tile 0 into plane 0 ----
  STAGE(gA,                   lds);
  STAGE(gA + 128 * (size_t)K, lds + 8192);
  STAGE(gB,                   lds + 32768);
  STAGE(gB + 128 * (size_t)K, lds + 32768 + 8192);

  for (int u = 0; u < NT; ++u){
    const int par = u & 1, parn = par ^ 1;
    const ushort* lA = lds + par * 16384;
    const ushort* lB = lds + 32768 + par * 16384;
    ushort* sA = lds + parn * 16384;
    ushort* sB = lds + 32768 + parn * 16384;
    // tile boundary: own loads landed (vmcnt), everyone's published (barrier).
    // Only tile-u loads are outstanding here; tile u+1 is issued below.
    asm volatile("s_waitcnt vmcnt(0)" ::: "memory");
    asm volatile("s_barrier" ::: "memory");

    f16x8 bf[4];
    // -- phase 0: (mh0,kh0); read B(kh0); stage A halves of tile u+1
    {
      f16x8 af[4];
      readA(af, lA, 0, 0); readB(bf, lB, 0);
      if (u + 1 < NT){
        STAGE(gA + (size_t)(u + 1) * 64,                   sA);
        STAGE(gA + 128 * (size_t)K + (size_t)(u + 1) * 64, sA + 8192);
      }
      asm volatile("s_barrier" ::: "memory");
      __builtin_amdgcn_s_setprio(1);
#pragma unroll
      for (int m = 0; m < 4; ++m)
#pragma unroll
        for (int n = 0; n < 4; ++n)
          acc[m][n] = __builtin_amdgcn_mfma_f32_16x16x32_f16(af[m], bf[n], acc[m][n], 0, 0, 0);
      __builtin_amdgcn_s_setprio(0);
      asm volatile("s_barrier" ::: "memory");
    }
    // -- phase 1: (mh1,kh0); reuse bf; stage B halves of tile u+1
    {
      f16x8 af[4];
      readA(af, lA, 1, 0);
      if (u + 1 < NT){
        STAGE(gB + (size_t)(u + 1) * 64,                   sB);
        STAGE(gB + 128 * (size_t)K + (size_t)(u + 1) * 64, sB + 8192);
      }
      asm volatile("s_barrier" ::: "memory");
      __builtin_amdgcn_s_setprio(1);
#pragma unroll
      for (int m = 0; m < 4; ++m)
#pragma unroll
        for (int n = 0; n < 4; ++n)
          acc[4 + m][n] = __builtin_amdgcn_mfma_f32_16x16x32_f16(af[m], bf[n], acc[4 + m][n], 0, 0, 0);
      __builtin_amdgcn_s_setprio(0);
      asm volatile("s_barrier" ::: "memory");
    }
    // -- phase 2: (mh0,kh1); read B(kh1)
    {
      f16x8 af[4];
      readA(af, lA, 0, 1); readB(bf, lB, 1);
      asm volatile("s_barrier" ::: "memory");
      __builtin_amdgcn_s_setprio(1);
#pragma unroll
      for (int m = 0; m < 4; ++m)
#pragma unroll
        for (int n = 0; n < 4; ++n)
          acc[m][n] = __builtin_amdgcn_mfma_f32_16x16x32_f16(af[m], bf[n], acc[m][n], 0, 0, 0);
      __builtin_amdgcn_s_setprio(0);
      asm volatile("s_barrier" ::: "memory");
    }
    // -- phase 3: (mh1,kh1); reuse bf
    {
      f16x8 af[4];
      readA(af, lA, 1, 1);
      asm volatile("s_barrier" ::: "memory");
      __builtin_amdgcn_s_setprio(1);
#pragma unroll
      for (int m = 0; m < 4; ++m)
#pragma unroll
        for (int n = 0; n < 4; ++n)
          acc[4 + m][n] = __builtin_amdgcn_mfma_f32_16x16x32_f16(af[m], bf[n], acc[4 + m][n], 0, 0, 0);
      __builtin_amdgcn_s_setprio(0);
      asm volatile("s_barrier" ::: "memory");
    }
  }

  // ---- epilogue: act -> fp16 -> LDS [256][256] (XOR swizzle) -> coalesced stores --
  // Last phase ended with s_barrier; all waves' LDS reads are complete.
  const int rowbase = wm * 128 + lnHi * 4;
  const int colbase = wn * 64 + ln15;
#pragma unroll
  for (int j = 0; j < 4; ++j){
    const int col = colbase + j * 16;
    const float bv = bias[n0 + col];
#pragma unroll
    for (int i = 0; i < 8; ++i){
#pragma unroll
      for (int r = 0; r < 4; ++r){
        const int row = rowbase + i * 16 + r;
        const float v = acc[i][j][r] + bv;
        float a;
        if (MODE == 0){
          const float th = 1.f - 2.f / (__expf(2.f * v) + 1.f);  // tanh(v)
          a = v > 0.f ? v * 0.9f + th * 0.1f : th * 0.5f;
        } else {
          a = v > 0.f ? v : 0.f;
        }
        const _Float16 h = (_Float16)a;
        lds[row * 256 + (col ^ ((row & 7) << 3))] = __builtin_bit_cast(ushort, h);
      }
    }
  }
  __syncthreads();
#pragma unroll
  for (int it = 0; it < 16; ++it){
    const int chunk = it * 512 + t;            // 256 rows x 32 chunks of 8 halfwords
    const int row = chunk >> 5, g = chunk & 31;
    const s16x8 vv = *(const s16x8*)&lds[row * 256 + ((g ^ (row & 7)) << 3)];
    *(s16x8*)&out[(size_t)(m0 + row) * N + n0 + (g << 3)] = vv;
  }
}

// ---------------- tiny GEMM3: out[32768][10] = h2 @ W3 + b3 (fp32 vector) ---------
__global__ void gemm3(const ushort* __restrict__ h2, const float* __restrict__ W3T,
                      const float* __restrict__ b3, float* __restrict__ out){
  const int lane = threadIdx.x & 63;
  const int row = blockIdx.x * 4 + (threadIdx.x >> 6);  // one wave per row
  const f16x8 hv = *(const f16x8*)(h2 + (size_t)row * 512 + lane * 8);
  float hf[8];
#pragma unroll
  for (int j = 0; j < 8; ++j) hf[j] = (float)hv[j];
  float acc[10];
#pragma unroll
  for (int c = 0; c < 10; ++c){
    const f32x4 w0 = *(const f32x4*)(W3T + c * 512 + lane * 8);
    const f32x4 w1 = *(const f32x4*)(W3T + c * 512 + lane * 8 + 4);
    float a = 0.f;
#pragma unroll
    for (int j = 0; j < 4; ++j) a += hf[j] * w0[j];
#pragma unroll
    for (int j = 0; j < 4; ++j) a += hf[4 + j] * w1[j];
    acc[c] = a;
  }
#pragma unroll
  for (int off = 32; off; off >>= 1)
#pragma unroll
    for (int c = 0; c < 10; ++c) acc[c] += __shfl_xor(acc[c], off);
  if (lane == 0){
#pragma unroll
    for (int c = 0; c < 10; ++c) out[(size_t)row * 10 + c] = acc[c] + b3[c];
  }
}

extern "C" void kernel_launch(void* const* d_in, const int* in_sizes, int n_in,
                              void* d_out, int out_size, void* d_ws, size_t ws_size,
                              hipStream_t stream){
  const float* x  = (const float*)d_in[0];
  const float* W1 = (const float*)d_in[1];
  const float* b1 = (const float*)d_in[2];
  const float* W2 = (const float*)d_in[3];
  const float* b2 = (const float*)d_in[4];
  const float* W3 = (const float*)d_in[5];
  const float* b3 = (const float*)d_in[6];
  float* out = (float*)d_out;

  const int B = 32768, Din = 512, H = 1024, Hh = 512;
  char* ws = (char*)d_ws;
  const size_t MB = (size_t)1 << 20;
  // ws layout (~99 MB):
  ushort* h1  = (ushort*)(ws);            // 64 MB  (32768 x 1024 fp16)
  ushort* xf  = (ushort*)(ws + 64 * MB);  // 32 MB  (32768 x 512 fp16; reused as h2)
  ushort* h2  = xf;
  ushort* W1T = (ushort*)(ws + 96 * MB);  // 1 MB   (1024 x 512 fp16)
  ushort* W2T = (ushort*)(ws + 97 * MB);  // 1 MB   (512 x 1024 fp16)
  float*  W3T = (float*)(ws + 98 * MB);   // 20 KB  (10 x 512 f32)

  convert_f16<<<(B * Din / 4 + 255) / 256, 256, 0, stream>>>(x, xf, B * Din / 4);
  transpose_f16<<<dim3(H / 32, Din / 32), 256, 0, stream>>>(W1, W1T, Din, H);
  transpose_f16<<<dim3(Hh / 32, H / 32), 256, 0, stream>>>(W2, W2T, H, Hh);
  transpose_w3<<<1, 512, 0, stream>>>(W3, W3T);

  gemm_f16_256<0><<<dim3(H / 256, B / 256), 512, 0, stream>>>(xf, W1T, b1, h1, H, Din);
  gemm_f16_256<1><<<dim3(Hh / 256, B / 256), 512, 0, stream>>>(h1, W2T, b2, h2, Hh, H);
  gemm3<<<B / 4, 256, 0, stream>>>(h2, W3T, b3, out);
}